// Round 1
// baseline (604.916 us; speedup 1.0000x reference)
//
#include <hip/hip_runtime.h>
#include <hip/hip_bf16.h>
#include <math.h>

#define N_NODES 100000
#define N_EDGES 1000000
#define D 64

// ---------------------------------------------------------------------------
// edge_agg: for edges with edge_type == rel, atomically add row h[dst] into
// agg[src]. One lane per edge for the type check; all 64 lanes of the wave
// cooperate on each matching edge's 64-float row (one float per lane).
// ---------------------------------------------------------------------------
__global__ __launch_bounds__(256) void edge_agg_kernel(
    const int* __restrict__ src, const int* __restrict__ dst,
    const int* __restrict__ etype, int rel, int nE,
    const float* __restrict__ h, float* __restrict__ agg)
{
    int wid  = (blockIdx.x * blockDim.x + threadIdx.x) >> 6;  // global wave id
    int lane = threadIdx.x & 63;
    int e = wid * 64 + lane;

    int s = 0, d = 0;
    bool act = false;
    if (e < nE) {
        act = (etype[e] == rel);
        if (act) { s = src[e]; d = dst[e]; }
    }
    unsigned long long m = __ballot(act);
    while (m) {
        int b = __ffsll(m) - 1;
        m &= (m - 1);
        int sb = __shfl(s, b);
        int db = __shfl(d, b);
        float v = h[(size_t)db * D + lane];
        atomicAdd(&agg[(size_t)sb * D + lane], v);
    }
}

// ---------------------------------------------------------------------------
// node_update: h_out[n] = relu(agg[n] @ W + h_in[n] @ root + b)
// One wave per node. Input rows broadcast via __shfl; weights read through L1.
// ---------------------------------------------------------------------------
__global__ __launch_bounds__(256) void node_update_kernel(
    const float* __restrict__ agg, const float* __restrict__ hin,
    const float* __restrict__ W, const float* __restrict__ root,
    const float* __restrict__ b, float* __restrict__ hout, int nN)
{
    int wid  = (blockIdx.x * blockDim.x + threadIdx.x) >> 6;
    int lane = threadIdx.x & 63;
    if (wid >= nN) return;

    size_t base = (size_t)wid * D;
    float a  = agg[base + lane];
    float hv = hin[base + lane];
    float acc = b[lane];
#pragma unroll
    for (int k = 0; k < D; ++k) {
        acc = fmaf(__shfl(a,  k), W[k * D + lane],    acc);
        acc = fmaf(__shfl(hv, k), root[k * D + lane], acc);
    }
    hout[base + lane] = fmaxf(acc, 0.0f);
}

// ---------------------------------------------------------------------------
// final: logits = h @ Wl + bl  (64 -> 16), then log_softmax over the 16 dims.
// One wave per node. Lane (g,j), g=lane>>4, j=lane&15: partial over k in
// [16g,16g+16), then xor-reduce across g; softmax across the 16-lane group.
// ---------------------------------------------------------------------------
__global__ __launch_bounds__(256) void final_kernel(
    const float* __restrict__ h, const float* __restrict__ Wl,
    const float* __restrict__ bl, float* __restrict__ out, int nN)
{
    int wid  = (blockIdx.x * blockDim.x + threadIdx.x) >> 6;
    int lane = threadIdx.x & 63;
    if (wid >= nN) return;

    float v = h[(size_t)wid * D + lane];
    int g = lane >> 4;
    int j = lane & 15;

    float p = 0.0f;
#pragma unroll
    for (int m = 0; m < 16; ++m) {
        int k = g * 16 + m;
        p = fmaf(__shfl(v, k), Wl[k * 16 + j], p);
    }
    // reduce partials across the 4 groups (same j)
    p += __shfl_xor(p, 16);
    p += __shfl_xor(p, 32);
    p += bl[j];

    // log_softmax across the 16-lane group
    float mx = p;
    mx = fmaxf(mx, __shfl_xor(mx, 1));
    mx = fmaxf(mx, __shfl_xor(mx, 2));
    mx = fmaxf(mx, __shfl_xor(mx, 4));
    mx = fmaxf(mx, __shfl_xor(mx, 8));
    float ex = __expf(p - mx);
    float sum = ex;
    sum += __shfl_xor(sum, 1);
    sum += __shfl_xor(sum, 2);
    sum += __shfl_xor(sum, 4);
    sum += __shfl_xor(sum, 8);
    float r = (p - mx) - logf(sum);
    if (lane < 16) out[(size_t)wid * 16 + j] = r;
}

extern "C" void kernel_launch(void* const* d_in, const int* in_sizes, int n_in,
                              void* d_out, int out_size, void* d_ws, size_t ws_size,
                              hipStream_t stream) {
    const float* x     = (const float*)d_in[0];
    const int*   ei    = (const int*)  d_in[1];   // [2, E]
    const int*   et    = (const int*)  d_in[2];   // [E]
    const float* W1    = (const float*)d_in[3];   // [5,64,64]
    const float* root1 = (const float*)d_in[4];   // [64,64]
    const float* b1    = (const float*)d_in[5];   // [64]
    const float* W2    = (const float*)d_in[6];   // [5,64,64]
    const float* root2 = (const float*)d_in[7];   // [64,64]
    const float* b2    = (const float*)d_in[8];   // [64]
    const float* Wl    = (const float*)d_in[9];   // [64,16]
    const float* bl    = (const float*)d_in[10];  // [16]
    float* out = (float*)d_out;

    const int N = N_NODES, E = N_EDGES;
    const size_t nodeBytes = (size_t)N * D * sizeof(float);

    char* ws  = (char*)d_ws;
    float* h_a = (float*)(ws);
    float* h_b = (float*)(ws + nodeBytes);
    float* agg = (float*)(ws + 2 * nodeBytes);

    const int* src = ei;       // edge_index[0]
    const int* dst = ei + E;   // edge_index[1]

    const int edgeWaves  = (E + 63) / 64;
    const int edgeBlocks = (edgeWaves + 3) / 4;   // 256 threads = 4 waves
    const int nodeBlocks = (N + 3) / 4;

    // ---- layer 0: rel 0, W1/root1/b1, x -> h_a
    hipMemsetAsync(agg, 0, nodeBytes, stream);
    edge_agg_kernel<<<edgeBlocks, 256, 0, stream>>>(src, dst, et, 0, E, x, agg);
    node_update_kernel<<<nodeBlocks, 256, 0, stream>>>(agg, x, W1 + 0 * D * D, root1, b1, h_a, N);

    // ---- layer 1: rel 1, W2/root2/b2, h_a -> h_b
    hipMemsetAsync(agg, 0, nodeBytes, stream);
    edge_agg_kernel<<<edgeBlocks, 256, 0, stream>>>(src, dst, et, 1, E, h_a, agg);
    node_update_kernel<<<nodeBlocks, 256, 0, stream>>>(agg, h_a, W2 + 1 * D * D, root2, b2, h_b, N);

    // ---- layer 2: rel 2, W2/root2/b2, h_b -> h_a
    hipMemsetAsync(agg, 0, nodeBytes, stream);
    edge_agg_kernel<<<edgeBlocks, 256, 0, stream>>>(src, dst, et, 2, E, h_b, agg);
    node_update_kernel<<<nodeBlocks, 256, 0, stream>>>(agg, h_b, W2 + 2 * D * D, root2, b2, h_a, N);

    // ---- final linear + log_softmax: h_a -> out
    final_kernel<<<nodeBlocks, 256, 0, stream>>>(h_a, Wl, bl, out, N);
}

// Round 2
// 399.875 us; speedup vs baseline: 1.5128x; 1.5128x over previous
//
#include <hip/hip_runtime.h>
#include <hip/hip_bf16.h>
#include <math.h>

#define N_NODES 100000
#define N_EDGES 1000000
#define D 64

// ---------------------------------------------------------------------------
// edge_agg: for edges with edge_type == rel, atomically add row h[dst] into
// agg[src]. One lane per edge for the type check; all 64 lanes of the wave
// cooperate on each matching edge's 64-float row (one float per lane).
// ---------------------------------------------------------------------------
__global__ __launch_bounds__(256) void edge_agg_kernel(
    const int* __restrict__ src, const int* __restrict__ dst,
    const int* __restrict__ etype, int rel, int nE,
    const float* __restrict__ h, float* __restrict__ agg)
{
    int wid  = (blockIdx.x * blockDim.x + threadIdx.x) >> 6;  // global wave id
    int lane = threadIdx.x & 63;
    int e = wid * 64 + lane;

    int s = 0, d = 0;
    bool act = false;
    if (e < nE) {
        act = (etype[e] == rel);
        if (act) { s = src[e]; d = dst[e]; }
    }
    unsigned long long m = __ballot(act);
    while (m) {
        int b = __ffsll(m) - 1;
        m &= (m - 1);
        int sb = __shfl(s, b);
        int db = __shfl(d, b);
        float v = h[(size_t)db * D + lane];
        atomicAdd(&agg[(size_t)sb * D + lane], v);
    }
}

// ---------------------------------------------------------------------------
// node_update: h_out[n] = relu(agg[n] @ W + h_in[n] @ root + b)
// One wave per node iteration (grid-stride). Lane j = output feature j.
// Weights held in registers (w[k] = W[k][j], r[k] = root[k][j]; 128 VGPRs),
// loaded ONCE per wave and reused across all nodes the wave processes.
// Input rows are wave-uniform: readfirstlane(n) gives an SGPR row pointer so
// the row reads become scalar loads (no shuffles, no ds pipe). Four
// accumulators break the serial FMA dependency chain.
// ---------------------------------------------------------------------------
__global__ __launch_bounds__(256) void node_update_kernel(
    const float* __restrict__ agg, const float* __restrict__ hin,
    const float* __restrict__ W, const float* __restrict__ root,
    const float* __restrict__ b, float* __restrict__ hout,
    int nN, int nWaves)
{
    int wid  = (blockIdx.x * blockDim.x + threadIdx.x) >> 6;
    int lane = threadIdx.x & 63;

    // per-lane weight columns, resident in VGPRs
    float w[D], r[D];
#pragma unroll
    for (int k = 0; k < D; ++k) {
        w[k] = W[k * D + lane];
        r[k] = root[k * D + lane];
    }
    float bias = b[lane];

    for (int n0 = wid; n0 < nN; n0 += nWaves) {
        int n = __builtin_amdgcn_readfirstlane(n0);   // wave-uniform -> SGPR
        const float4* arow = (const float4*)(agg + (size_t)n * D);
        const float4* hrow = (const float4*)(hin + (size_t)n * D);

        float a0 = bias, a1 = 0.f, a2 = 0.f, a3 = 0.f;
#pragma unroll
        for (int q = 0; q < D / 4; ++q) {
            float4 av = arow[q];
            float4 hv = hrow[q];
            a0 = fmaf(av.x, w[4*q+0], a0);
            a1 = fmaf(av.y, w[4*q+1], a1);
            a2 = fmaf(av.z, w[4*q+2], a2);
            a3 = fmaf(av.w, w[4*q+3], a3);
            a0 = fmaf(hv.x, r[4*q+0], a0);
            a1 = fmaf(hv.y, r[4*q+1], a1);
            a2 = fmaf(hv.z, r[4*q+2], a2);
            a3 = fmaf(hv.w, r[4*q+3], a3);
        }
        hout[(size_t)n * D + lane] = fmaxf((a0 + a1) + (a2 + a3), 0.f);
    }
}

// ---------------------------------------------------------------------------
// final: logits = h @ Wl + bl  (64 -> 16), then log_softmax over the 16 dims.
// One wave per node. Lane (g,j), g=lane>>4, j=lane&15: partial over k in
// [16g,16g+16), then xor-reduce across g; softmax across the 16-lane group.
// ---------------------------------------------------------------------------
__global__ __launch_bounds__(256) void final_kernel(
    const float* __restrict__ h, const float* __restrict__ Wl,
    const float* __restrict__ bl, float* __restrict__ out, int nN)
{
    int wid  = (blockIdx.x * blockDim.x + threadIdx.x) >> 6;
    int lane = threadIdx.x & 63;
    if (wid >= nN) return;

    float v = h[(size_t)wid * D + lane];
    int g = lane >> 4;
    int j = lane & 15;

    float p = 0.0f;
#pragma unroll
    for (int m = 0; m < 16; ++m) {
        int k = g * 16 + m;
        p = fmaf(__shfl(v, k), Wl[k * 16 + j], p);
    }
    // reduce partials across the 4 groups (same j)
    p += __shfl_xor(p, 16);
    p += __shfl_xor(p, 32);
    p += bl[j];

    // log_softmax across the 16-lane group
    float mx = p;
    mx = fmaxf(mx, __shfl_xor(mx, 1));
    mx = fmaxf(mx, __shfl_xor(mx, 2));
    mx = fmaxf(mx, __shfl_xor(mx, 4));
    mx = fmaxf(mx, __shfl_xor(mx, 8));
    float ex = __expf(p - mx);
    float sum = ex;
    sum += __shfl_xor(sum, 1);
    sum += __shfl_xor(sum, 2);
    sum += __shfl_xor(sum, 4);
    sum += __shfl_xor(sum, 8);
    float r = (p - mx) - logf(sum);
    if (lane < 16) out[(size_t)wid * 16 + j] = r;
}

extern "C" void kernel_launch(void* const* d_in, const int* in_sizes, int n_in,
                              void* d_out, int out_size, void* d_ws, size_t ws_size,
                              hipStream_t stream) {
    const float* x     = (const float*)d_in[0];
    const int*   ei    = (const int*)  d_in[1];   // [2, E]
    const int*   et    = (const int*)  d_in[2];   // [E]
    const float* W1    = (const float*)d_in[3];   // [5,64,64]
    const float* root1 = (const float*)d_in[4];   // [64,64]
    const float* b1    = (const float*)d_in[5];   // [64]
    const float* W2    = (const float*)d_in[6];   // [5,64,64]
    const float* root2 = (const float*)d_in[7];   // [64,64]
    const float* b2    = (const float*)d_in[8];   // [64]
    const float* Wl    = (const float*)d_in[9];   // [64,16]
    const float* bl    = (const float*)d_in[10];  // [16]
    float* out = (float*)d_out;

    const int N = N_NODES, E = N_EDGES;
    const size_t nodeBytes = (size_t)N * D * sizeof(float);

    char* ws  = (char*)d_ws;
    float* h_a = (float*)(ws);
    float* h_b = (float*)(ws + nodeBytes);
    float* agg = (float*)(ws + 2 * nodeBytes);

    const int* src = ei;       // edge_index[0]
    const int* dst = ei + E;   // edge_index[1]

    const int edgeWaves  = (E + 63) / 64;
    const int edgeBlocks = (edgeWaves + 3) / 4;   // 256 threads = 4 waves

    const int nodeBlocks = 1024;                  // grid-stride
    const int nodeWaves  = nodeBlocks * 4;

    const int finalBlocks = (N + 3) / 4;

    // ---- layer 0: rel 0, W1/root1/b1, x -> h_a
    hipMemsetAsync(agg, 0, nodeBytes, stream);
    edge_agg_kernel<<<edgeBlocks, 256, 0, stream>>>(src, dst, et, 0, E, x, agg);
    node_update_kernel<<<nodeBlocks, 256, 0, stream>>>(agg, x, W1 + 0 * D * D, root1, b1, h_a, N, nodeWaves);

    // ---- layer 1: rel 1, W2/root2/b2, h_a -> h_b
    hipMemsetAsync(agg, 0, nodeBytes, stream);
    edge_agg_kernel<<<edgeBlocks, 256, 0, stream>>>(src, dst, et, 1, E, h_a, agg);
    node_update_kernel<<<nodeBlocks, 256, 0, stream>>>(agg, h_a, W2 + 1 * D * D, root2, b2, h_b, N, nodeWaves);

    // ---- layer 2: rel 2, W2/root2/b2, h_b -> h_a
    hipMemsetAsync(agg, 0, nodeBytes, stream);
    edge_agg_kernel<<<edgeBlocks, 256, 0, stream>>>(src, dst, et, 2, E, h_b, agg);
    node_update_kernel<<<nodeBlocks, 256, 0, stream>>>(agg, h_b, W2 + 2 * D * D, root2, b2, h_a, N, nodeWaves);

    // ---- final linear + log_softmax: h_a -> out
    final_kernel<<<finalBlocks, 256, 0, stream>>>(h_a, Wl, bl, out, N);
}